// Round 10
// baseline (6452.451 us; speedup 1.0000x reference)
//
#include <hip/hip_runtime.h>

#define NROW 16

__device__ __forceinline__ float sigmoidf_(float x) {
    return 1.f / (1.f + expf(-x));
}

// ---------------------------------------------------------------------------
// Output layout (MEASURED, confirmed by R0/R4-6/R8/R9 fingerprints):
//   d_out = float32[5,242,880]  (out_size = 5,242,880; 21 MB buffer)
//   [0,      B*512) : recon (B,16,2,4,4) f32
//   [B*512,  B*640) : bases_all REAL PARTS (complex64 -> astype(float32)),
//                     flat = b*128 + t*8 + (q*4 + i*2 + j)
// Phases: 1) measurement LSTM cell + projector epilogue (15 steps),
//         2) two proj-LSTM layers (16 steps). 16 rows/block, 256 threads;
// thread t owns gate channel t (gate rows t, t+256, t+512, t+768).
// ---------------------------------------------------------------------------
__global__ __launch_bounds__(256)
void fused_kernel(const float* meas, const float* basis_ri, const float* rho,
                  const float* h0g, const float* c0g,
                  const float* Wih, const float* Whh, const float* bvec,
                  const float* projW, const float* projb,
                  const float* W0ih, const float* W0hh, const float* b0v, const float* W0hr,
                  const float* W1ih, const float* W1hh, const float* b1v, const float* W1hr,
                  float* recon, float* breal)
{
    __shared__ __align__(16) float hs[NROW][256];
    __shared__ __align__(16) float cs[NROW][256];
    __shared__ __align__(16) float seqs[NROW][16][17];
    __shared__ float vs[NROW][8];
    __shared__ __align__(16) float p0s[NROW][32];
    __shared__ __align__(16) float p1s[NROW][32];

    const int t = threadIdx.x;
    const int row0 = blockIdx.x * NROW;

    // ---------------- phase 1 init ----------------
    for (int r = 0; r < NROW; ++r) {
        hs[r][t] = h0g[(size_t)(row0 + r) * 256 + t];
        cs[r][t] = c0g[(size_t)(row0 + r) * 256 + t];
    }
    for (int idx = t; idx < NROW * 17; idx += 256) {
        int r = idx / 17, k = idx % 17;
        float val = (k == 0) ? meas[row0 + r]
                             : basis_ri[(size_t)(row0 + r) * 16 + (k - 1)];
        seqs[r][0][k] = val;
    }
    // t=0 bases: real parts of basis0 (basis_ri[..., 0], even ri index)
    if (t < 128) {
        int r = t >> 3, c = t & 7;   // c = q*4 + i*2 + j
        breal[(size_t)(row0 + r) * 128 + 0 * 8 + c] =
            basis_ri[(size_t)(row0 + r) * 16 + 2 * c];
    }
    __syncthreads();

    const float bg0 = bvec[t], bg1 = bvec[t + 256],
                bg2 = bvec[t + 512], bg3 = bvec[t + 768];

    // ---------------- phase 1: 15 steps ----------------
    for (int tt = 0; tt < 15; ++tt) {
        float a0[NROW], a1[NROW], a2[NROW], a3[NROW];
        #pragma unroll
        for (int r = 0; r < NROW; ++r) { a0[r] = bg0; a1[r] = bg1; a2[r] = bg2; a3[r] = bg3; }

        for (int k = 0; k < 17; ++k) {
            float w0 = Wih[(size_t)t * 17 + k];
            float w1 = Wih[(size_t)(t + 256) * 17 + k];
            float w2 = Wih[(size_t)(t + 512) * 17 + k];
            float w3 = Wih[(size_t)(t + 768) * 17 + k];
            #pragma unroll
            for (int r = 0; r < NROW; ++r) {
                float x = seqs[r][tt][k];
                a0[r] += w0 * x; a1[r] += w1 * x; a2[r] += w2 * x; a3[r] += w3 * x;
            }
        }
        for (int k = 0; k < 256; k += 4) {
            float4 w0 = *(const float4*)(Whh + (size_t)t * 256 + k);
            float4 w1 = *(const float4*)(Whh + (size_t)(t + 256) * 256 + k);
            float4 w2 = *(const float4*)(Whh + (size_t)(t + 512) * 256 + k);
            float4 w3 = *(const float4*)(Whh + (size_t)(t + 768) * 256 + k);
            #pragma unroll
            for (int r = 0; r < NROW; ++r) {
                float4 h = *(const float4*)(&hs[r][k]);
                a0[r] += w0.x*h.x + w0.y*h.y + w0.z*h.z + w0.w*h.w;
                a1[r] += w1.x*h.x + w1.y*h.y + w1.z*h.z + w1.w*h.w;
                a2[r] += w2.x*h.x + w2.y*h.y + w2.z*h.z + w2.w*h.w;
                a3[r] += w3.x*h.x + w3.y*h.y + w3.z*h.z + w3.w*h.w;
            }
        }
        __syncthreads();

        #pragma unroll
        for (int r = 0; r < NROW; ++r) {
            float cn = sigmoidf_(a1[r]) * cs[r][t] + sigmoidf_(a0[r]) * tanhf(a2[r]);
            cs[r][t] = cn;
            hs[r][t] = sigmoidf_(a3[r]) * tanhf(cn);
        }
        __syncthreads();

        if (t < 128) {
            int j = t >> 4, r = t & 15;
            const float* wrow = projW + j * 256;
            float s = projb[j];
            for (int k = 0; k < 256; k += 4) {
                float4 w = *(const float4*)(wrow + k);
                float4 h = *(const float4*)(&hs[r][k]);
                s += w.x*h.x + w.y*h.y + w.z*h.z + w.w*h.w;
            }
            vs[r][j] = s;
        }
        __syncthreads();

        if (t < NROW) {
            const int r = t;
            const int b = row0 + r;
            float v[8];
            #pragma unroll
            for (int j = 0; j < 8; ++j) v[j] = vs[r][j];

            float bre[2][2][2], bim[2][2][2];
            #pragma unroll
            for (int q = 0; q < 2; ++q) {
                float b0r = v[q*4+0], b0i = v[q*4+1];
                float b1r = v[q*4+2], b1i = v[q*4+3];
                float n0 = b0r*b0r + b0i*b0i;
                float n1 = b1r*b1r + b1i*b1i;
                float inv = 1.f / (n0 + n1);
                float xr = (b0r*b1r + b0i*b1i) * inv;
                float xi = (b0i*b1r - b0r*b1i) * inv;
                bre[q][0][0] = n0 * inv; bim[q][0][0] = 0.f;
                bre[q][1][1] = n1 * inv; bim[q][1][1] = 0.f;
                bre[q][0][1] = xr;       bim[q][0][1] = xi;
                bre[q][1][0] = xr;       bim[q][1][0] = -xi;
            }
            // m = Re sum bm0[i][j] * bm1[k][l] * rho_c[j*2+l][i*2+k]
            const float* rr_ = rho + (size_t)b * 32;  // [real 16][imag 16]
            float m = 0.f;
            #pragma unroll
            for (int i2 = 0; i2 < 2; ++i2)
            #pragma unroll
            for (int j2 = 0; j2 < 2; ++j2) {
                float ar = bre[0][i2][j2], ai = bim[0][i2][j2];
                #pragma unroll
                for (int kk = 0; kk < 2; ++kk)
                #pragma unroll
                for (int ll = 0; ll < 2; ++ll) {
                    float brr = bre[1][kk][ll], bii = bim[1][kk][ll];
                    float ur = ar*brr - ai*bii;
                    float ui = ar*bii + ai*brr;
                    int x = j2*2 + ll, y = i2*2 + kk;
                    m += ur * rr_[x*4 + y] - ui * rr_[16 + x*4 + y];
                }
            }
            seqs[r][tt + 1][0] = m;
            float* rp = breal + (size_t)b * 128 + (tt + 1) * 8;
            #pragma unroll
            for (int e = 0; e < 8; ++e) {
                int q = e >> 2, r2 = (e >> 1) & 1, c2 = e & 1;
                float re = bre[q][r2][c2], im = bim[q][r2][c2];
                seqs[r][tt + 1][1 + 2*e]     = re;
                seqs[r][tt + 1][1 + 2*e + 1] = im;
                rp[e] = re;                      // REAL PART ONLY
            }
        }
        __syncthreads();
    }

    // ---------------- phase 2 init ----------------
    float c20[NROW], c21[NROW];
    #pragma unroll
    for (int r = 0; r < NROW; ++r) { c20[r] = 0.f; c21[r] = 0.f; }
    for (int idx = t; idx < NROW * 32; idx += 256) {
        (&p0s[0][0])[idx] = 0.f;
        (&p1s[0][0])[idx] = 0.f;
    }
    __syncthreads();

    const float B00 = b0v[t], B01 = b0v[t+256], B02 = b0v[t+512], B03 = b0v[t+768];
    const float B10 = b1v[t], B11 = b1v[t+256], B12 = b1v[t+512], B13 = b1v[t+768];

    // ---------------- phase 2: 16 steps ----------------
    for (int tt = 0; tt < 16; ++tt) {
        {
            float a0[NROW], a1[NROW], a2[NROW], a3[NROW];
            #pragma unroll
            for (int r = 0; r < NROW; ++r) { a0[r]=B00; a1[r]=B01; a2[r]=B02; a3[r]=B03; }
            for (int k = 0; k < 17; ++k) {
                float w0 = W0ih[(size_t)t*17+k];
                float w1 = W0ih[(size_t)(t+256)*17+k];
                float w2 = W0ih[(size_t)(t+512)*17+k];
                float w3 = W0ih[(size_t)(t+768)*17+k];
                #pragma unroll
                for (int r = 0; r < NROW; ++r) {
                    float x = seqs[r][tt][k];
                    a0[r] += w0*x; a1[r] += w1*x; a2[r] += w2*x; a3[r] += w3*x;
                }
            }
            for (int k = 0; k < 32; ++k) {
                float w0 = W0hh[(size_t)t*32+k];
                float w1 = W0hh[(size_t)(t+256)*32+k];
                float w2 = W0hh[(size_t)(t+512)*32+k];
                float w3 = W0hh[(size_t)(t+768)*32+k];
                #pragma unroll
                for (int r = 0; r < NROW; ++r) {
                    float h = p0s[r][k];
                    a0[r] += w0*h; a1[r] += w1*h; a2[r] += w2*h; a3[r] += w3*h;
                }
            }
            __syncthreads();
            #pragma unroll
            for (int r = 0; r < NROW; ++r) {
                float cn = sigmoidf_(a1[r]) * c20[r] + sigmoidf_(a0[r]) * tanhf(a2[r]);
                c20[r] = cn;
                hs[r][t] = sigmoidf_(a3[r]) * tanhf(cn);
            }
        }
        __syncthreads();

        {
            int r = t & 15;
            int pbase = (t >> 4) * 2;
            #pragma unroll
            for (int i = 0; i < 2; ++i) {
                int p = pbase + i;
                const float* wrow = W0hr + p * 256;
                float s = 0.f;
                for (int k = 0; k < 256; k += 4) {
                    float4 w = *(const float4*)(wrow + k);
                    float4 h = *(const float4*)(&hs[r][k]);
                    s += w.x*h.x + w.y*h.y + w.z*h.z + w.w*h.w;
                }
                p0s[r][p] = s;
            }
        }
        __syncthreads();

        {
            float a0[NROW], a1[NROW], a2[NROW], a3[NROW];
            #pragma unroll
            for (int r = 0; r < NROW; ++r) { a0[r]=B10; a1[r]=B11; a2[r]=B12; a3[r]=B13; }
            for (int k = 0; k < 32; ++k) {
                float wi0 = W1ih[(size_t)t*32+k];
                float wi1 = W1ih[(size_t)(t+256)*32+k];
                float wi2 = W1ih[(size_t)(t+512)*32+k];
                float wi3 = W1ih[(size_t)(t+768)*32+k];
                float wh0 = W1hh[(size_t)t*32+k];
                float wh1 = W1hh[(size_t)(t+256)*32+k];
                float wh2 = W1hh[(size_t)(t+512)*32+k];
                float wh3 = W1hh[(size_t)(t+768)*32+k];
                #pragma unroll
                for (int r = 0; r < NROW; ++r) {
                    float x = p0s[r][k];
                    float h = p1s[r][k];
                    a0[r] += wi0*x + wh0*h;
                    a1[r] += wi1*x + wh1*h;
                    a2[r] += wi2*x + wh2*h;
                    a3[r] += wi3*x + wh3*h;
                }
            }
            __syncthreads();
            #pragma unroll
            for (int r = 0; r < NROW; ++r) {
                float cn = sigmoidf_(a1[r]) * c21[r] + sigmoidf_(a0[r]) * tanhf(a2[r]);
                c21[r] = cn;
                hs[r][t] = sigmoidf_(a3[r]) * tanhf(cn);
            }
        }
        __syncthreads();

        {
            int r = t & 15;
            int pbase = (t >> 4) * 2;
            #pragma unroll
            for (int i = 0; i < 2; ++i) {
                int p = pbase + i;
                const float* wrow = W1hr + p * 256;
                float s = 0.f;
                for (int k = 0; k < 256; k += 4) {
                    float4 w = *(const float4*)(wrow + k);
                    float4 h = *(const float4*)(&hs[r][k]);
                    s += w.x*h.x + w.y*h.y + w.z*h.z + w.w*h.w;
                }
                p1s[r][p] = s;
                recon[((size_t)(row0 + r) * 16 + tt) * 32 + p] = s;
            }
        }
        __syncthreads();
    }
}

// ---------------------------------------------------------------------------
extern "C" void kernel_launch(void* const* d_in, const int* in_sizes, int n_in,
                              void* d_out, int out_size, void* d_ws, size_t ws_size,
                              hipStream_t stream)
{
    const float* meas  = (const float*)d_in[0];
    const float* basis = (const float*)d_in[1];
    const float* rho   = (const float*)d_in[2];
    const float* h0    = (const float*)d_in[3];
    const float* c0    = (const float*)d_in[4];
    const float* cWih  = (const float*)d_in[5];
    const float* cWhh  = (const float*)d_in[6];
    const float* cb    = (const float*)d_in[7];
    const float* pW    = (const float*)d_in[8];
    const float* pb    = (const float*)d_in[9];
    const float* l0Wih = (const float*)d_in[10];
    const float* l0Whh = (const float*)d_in[11];
    const float* l0b   = (const float*)d_in[12];
    const float* l0Whr = (const float*)d_in[13];
    const float* l1Wih = (const float*)d_in[14];
    const float* l1Whh = (const float*)d_in[15];
    const float* l1b   = (const float*)d_in[16];
    const float* l1Whr = (const float*)d_in[17];

    const int B = in_sizes[0];  // 8192

    float* recon = (float*)d_out;                        // B*512 f32
    float* breal = (float*)d_out + (size_t)B * 512;      // B*128 f32 (real parts)

    fused_kernel<<<B / NROW, 256, 0, stream>>>(meas, basis, rho, h0, c0,
                                               cWih, cWhh, cb, pW, pb,
                                               l0Wih, l0Whh, l0b, l0Whr,
                                               l1Wih, l1Whh, l1b, l1Whr,
                                               recon, breal);
}

// Round 12
// 6329.959 us; speedup vs baseline: 1.0194x; 1.0194x over previous
//
#include <hip/hip_runtime.h>

#define NROW 16
#define HPAD 260   // hs row stride: breaks the 1024B-stride 16-way bank conflict

__device__ __forceinline__ float sigmoidf_(float x) {
    return 1.f / (1.f + expf(-x));
}

// ---------------------------------------------------------------------------
// Output layout (MEASURED): d_out = float32[5,242,880]
//   [0,      B*512) : recon (B,16,2,4,4) f32
//   [B*512,  B*640) : bases_all REAL PARTS, flat = b*128 + t*8 + (q*4+i*2+j)
// R10 baseline: 6452us, VALUBusy 24%, bank-conflict 8.19e8, occ 11.4%.
// R11 changes (resubmit; R11 was an acquisition timeout): (1) hs padded to
// 260 -> proj ds_read_b128 conflicts ~gone; (2) phase-1 c state LDS->regs
// (-16KB LDS); (3) launch_bounds(256,3) for 3 blocks/CU; (4) vs padded to 9.
// ---------------------------------------------------------------------------
__global__ __launch_bounds__(256, 3)
void fused_kernel(const float* meas, const float* basis_ri, const float* rho,
                  const float* h0g, const float* c0g,
                  const float* Wih, const float* Whh, const float* bvec,
                  const float* projW, const float* projb,
                  const float* W0ih, const float* W0hh, const float* b0v, const float* W0hr,
                  const float* W1ih, const float* W1hh, const float* b1v, const float* W1hr,
                  float* recon, float* breal)
{
    __shared__ __align__(16) float hs[NROW][HPAD];
    __shared__ __align__(16) float seqs[NROW][16][17];
    __shared__ float vs[NROW][9];
    __shared__ __align__(16) float p0s[NROW][32];
    __shared__ __align__(16) float p1s[NROW][32];

    const int t = threadIdx.x;
    const int row0 = blockIdx.x * NROW;

    // ---------------- phase 1 init ----------------
    float creg[NROW];            // c state: thread t owns channel t of each row
    for (int r = 0; r < NROW; ++r) {
        hs[r][t]  = h0g[(size_t)(row0 + r) * 256 + t];
        creg[r]   = c0g[(size_t)(row0 + r) * 256 + t];
    }
    for (int idx = t; idx < NROW * 17; idx += 256) {
        int r = idx / 17, k = idx % 17;
        float val = (k == 0) ? meas[row0 + r]
                             : basis_ri[(size_t)(row0 + r) * 16 + (k - 1)];
        seqs[r][0][k] = val;
    }
    // t=0 bases: real parts of basis0 (even ri index)
    if (t < 128) {
        int r = t >> 3, c = t & 7;   // c = q*4 + i*2 + j
        breal[(size_t)(row0 + r) * 128 + 0 * 8 + c] =
            basis_ri[(size_t)(row0 + r) * 16 + 2 * c];
    }
    __syncthreads();

    const float bg0 = bvec[t], bg1 = bvec[t + 256],
                bg2 = bvec[t + 512], bg3 = bvec[t + 768];

    // ---------------- phase 1: 15 steps ----------------
    for (int tt = 0; tt < 15; ++tt) {
        float a0[NROW], a1[NROW], a2[NROW], a3[NROW];
        #pragma unroll
        for (int r = 0; r < NROW; ++r) { a0[r] = bg0; a1[r] = bg1; a2[r] = bg2; a3[r] = bg3; }

        for (int k = 0; k < 17; ++k) {
            float w0 = Wih[(size_t)t * 17 + k];
            float w1 = Wih[(size_t)(t + 256) * 17 + k];
            float w2 = Wih[(size_t)(t + 512) * 17 + k];
            float w3 = Wih[(size_t)(t + 768) * 17 + k];
            #pragma unroll
            for (int r = 0; r < NROW; ++r) {
                float x = seqs[r][tt][k];
                a0[r] += w0 * x; a1[r] += w1 * x; a2[r] += w2 * x; a3[r] += w3 * x;
            }
        }
        for (int k = 0; k < 256; k += 4) {
            float4 w0 = *(const float4*)(Whh + (size_t)t * 256 + k);
            float4 w1 = *(const float4*)(Whh + (size_t)(t + 256) * 256 + k);
            float4 w2 = *(const float4*)(Whh + (size_t)(t + 512) * 256 + k);
            float4 w3 = *(const float4*)(Whh + (size_t)(t + 768) * 256 + k);
            #pragma unroll
            for (int r = 0; r < NROW; ++r) {
                float4 h = *(const float4*)(&hs[r][k]);
                a0[r] += w0.x*h.x + w0.y*h.y + w0.z*h.z + w0.w*h.w;
                a1[r] += w1.x*h.x + w1.y*h.y + w1.z*h.z + w1.w*h.w;
                a2[r] += w2.x*h.x + w2.y*h.y + w2.z*h.z + w2.w*h.w;
                a3[r] += w3.x*h.x + w3.y*h.y + w3.z*h.z + w3.w*h.w;
            }
        }
        __syncthreads();

        #pragma unroll
        for (int r = 0; r < NROW; ++r) {
            float cn = sigmoidf_(a1[r]) * creg[r] + sigmoidf_(a0[r]) * tanhf(a2[r]);
            creg[r] = cn;
            hs[r][t] = sigmoidf_(a3[r]) * tanhf(cn);
        }
        __syncthreads();

        if (t < 128) {
            int j = t >> 4, r = t & 15;
            const float* wrow = projW + j * 256;
            float s = projb[j];
            for (int k = 0; k < 256; k += 4) {
                float4 w = *(const float4*)(wrow + k);
                float4 h = *(const float4*)(&hs[r][k]);
                s += w.x*h.x + w.y*h.y + w.z*h.z + w.w*h.w;
            }
            vs[r][j] = s;
        }
        __syncthreads();

        if (t < NROW) {
            const int r = t;
            const int b = row0 + r;
            float v[8];
            #pragma unroll
            for (int j = 0; j < 8; ++j) v[j] = vs[r][j];

            float bre[2][2][2], bim[2][2][2];
            #pragma unroll
            for (int q = 0; q < 2; ++q) {
                float b0r = v[q*4+0], b0i = v[q*4+1];
                float b1r = v[q*4+2], b1i = v[q*4+3];
                float n0 = b0r*b0r + b0i*b0i;
                float n1 = b1r*b1r + b1i*b1i;
                float inv = 1.f / (n0 + n1);
                float xr = (b0r*b1r + b0i*b1i) * inv;
                float xi = (b0i*b1r - b0r*b1i) * inv;
                bre[q][0][0] = n0 * inv; bim[q][0][0] = 0.f;
                bre[q][1][1] = n1 * inv; bim[q][1][1] = 0.f;
                bre[q][0][1] = xr;       bim[q][0][1] = xi;
                bre[q][1][0] = xr;       bim[q][1][0] = -xi;
            }
            // m = Re sum bm0[i][j] * bm1[k][l] * rho_c[j*2+l][i*2+k]
            const float* rr_ = rho + (size_t)b * 32;  // [real 16][imag 16]
            float m = 0.f;
            #pragma unroll
            for (int i2 = 0; i2 < 2; ++i2)
            #pragma unroll
            for (int j2 = 0; j2 < 2; ++j2) {
                float ar = bre[0][i2][j2], ai = bim[0][i2][j2];
                #pragma unroll
                for (int kk = 0; kk < 2; ++kk)
                #pragma unroll
                for (int ll = 0; ll < 2; ++ll) {
                    float brr = bre[1][kk][ll], bii = bim[1][kk][ll];
                    float ur = ar*brr - ai*bii;
                    float ui = ar*bii + ai*brr;
                    int x = j2*2 + ll, y = i2*2 + kk;
                    m += ur * rr_[x*4 + y] - ui * rr_[16 + x*4 + y];
                }
            }
            seqs[r][tt + 1][0] = m;
            float* rp = breal + (size_t)b * 128 + (tt + 1) * 8;
            #pragma unroll
            for (int e = 0; e < 8; ++e) {
                int q = e >> 2, r2 = (e >> 1) & 1, c2 = e & 1;
                float re = bre[q][r2][c2], im = bim[q][r2][c2];
                seqs[r][tt + 1][1 + 2*e]     = re;
                seqs[r][tt + 1][1 + 2*e + 1] = im;
                rp[e] = re;                      // REAL PART ONLY
            }
        }
        __syncthreads();
    }

    // ---------------- phase 2 init ----------------
    float c20[NROW], c21[NROW];
    #pragma unroll
    for (int r = 0; r < NROW; ++r) { c20[r] = 0.f; c21[r] = 0.f; }
    for (int idx = t; idx < NROW * 32; idx += 256) {
        (&p0s[0][0])[idx] = 0.f;
        (&p1s[0][0])[idx] = 0.f;
    }
    __syncthreads();

    const float B00 = b0v[t], B01 = b0v[t+256], B02 = b0v[t+512], B03 = b0v[t+768];
    const float B10 = b1v[t], B11 = b1v[t+256], B12 = b1v[t+512], B13 = b1v[t+768];

    // ---------------- phase 2: 16 steps ----------------
    for (int tt = 0; tt < 16; ++tt) {
        {
            float a0[NROW], a1[NROW], a2[NROW], a3[NROW];
            #pragma unroll
            for (int r = 0; r < NROW; ++r) { a0[r]=B00; a1[r]=B01; a2[r]=B02; a3[r]=B03; }
            for (int k = 0; k < 17; ++k) {
                float w0 = W0ih[(size_t)t*17+k];
                float w1 = W0ih[(size_t)(t+256)*17+k];
                float w2 = W0ih[(size_t)(t+512)*17+k];
                float w3 = W0ih[(size_t)(t+768)*17+k];
                #pragma unroll
                for (int r = 0; r < NROW; ++r) {
                    float x = seqs[r][tt][k];
                    a0[r] += w0*x; a1[r] += w1*x; a2[r] += w2*x; a3[r] += w3*x;
                }
            }
            for (int k = 0; k < 32; ++k) {
                float w0 = W0hh[(size_t)t*32+k];
                float w1 = W0hh[(size_t)(t+256)*32+k];
                float w2 = W0hh[(size_t)(t+512)*32+k];
                float w3 = W0hh[(size_t)(t+768)*32+k];
                #pragma unroll
                for (int r = 0; r < NROW; ++r) {
                    float h = p0s[r][k];
                    a0[r] += w0*h; a1[r] += w1*h; a2[r] += w2*h; a3[r] += w3*h;
                }
            }
            __syncthreads();
            #pragma unroll
            for (int r = 0; r < NROW; ++r) {
                float cn = sigmoidf_(a1[r]) * c20[r] + sigmoidf_(a0[r]) * tanhf(a2[r]);
                c20[r] = cn;
                hs[r][t] = sigmoidf_(a3[r]) * tanhf(cn);
            }
        }
        __syncthreads();

        {
            int r = t & 15;
            int pbase = (t >> 4) * 2;
            #pragma unroll
            for (int i = 0; i < 2; ++i) {
                int p = pbase + i;
                const float* wrow = W0hr + p * 256;
                float s = 0.f;
                for (int k = 0; k < 256; k += 4) {
                    float4 w = *(const float4*)(wrow + k);
                    float4 h = *(const float4*)(&hs[r][k]);
                    s += w.x*h.x + w.y*h.y + w.z*h.z + w.w*h.w;
                }
                p0s[r][p] = s;
            }
        }
        __syncthreads();

        {
            float a0[NROW], a1[NROW], a2[NROW], a3[NROW];
            #pragma unroll
            for (int r = 0; r < NROW; ++r) { a0[r]=B10; a1[r]=B11; a2[r]=B12; a3[r]=B13; }
            for (int k = 0; k < 32; ++k) {
                float wi0 = W1ih[(size_t)t*32+k];
                float wi1 = W1ih[(size_t)(t+256)*32+k];
                float wi2 = W1ih[(size_t)(t+512)*32+k];
                float wi3 = W1ih[(size_t)(t+768)*32+k];
                float wh0 = W1hh[(size_t)t*32+k];
                float wh1 = W1hh[(size_t)(t+256)*32+k];
                float wh2 = W1hh[(size_t)(t+512)*32+k];
                float wh3 = W1hh[(size_t)(t+768)*32+k];
                #pragma unroll
                for (int r = 0; r < NROW; ++r) {
                    float x = p0s[r][k];
                    float h = p1s[r][k];
                    a0[r] += wi0*x + wh0*h;
                    a1[r] += wi1*x + wh1*h;
                    a2[r] += wi2*x + wh2*h;
                    a3[r] += wi3*x + wh3*h;
                }
            }
            __syncthreads();
            #pragma unroll
            for (int r = 0; r < NROW; ++r) {
                float cn = sigmoidf_(a1[r]) * c21[r] + sigmoidf_(a0[r]) * tanhf(a2[r]);
                c21[r] = cn;
                hs[r][t] = sigmoidf_(a3[r]) * tanhf(cn);
            }
        }
        __syncthreads();

        {
            int r = t & 15;
            int pbase = (t >> 4) * 2;
            #pragma unroll
            for (int i = 0; i < 2; ++i) {
                int p = pbase + i;
                const float* wrow = W1hr + p * 256;
                float s = 0.f;
                for (int k = 0; k < 256; k += 4) {
                    float4 w = *(const float4*)(wrow + k);
                    float4 h = *(const float4*)(&hs[r][k]);
                    s += w.x*h.x + w.y*h.y + w.z*h.z + w.w*h.w;
                }
                p1s[r][p] = s;
                recon[((size_t)(row0 + r) * 16 + tt) * 32 + p] = s;
            }
        }
        __syncthreads();
    }
}

// ---------------------------------------------------------------------------
extern "C" void kernel_launch(void* const* d_in, const int* in_sizes, int n_in,
                              void* d_out, int out_size, void* d_ws, size_t ws_size,
                              hipStream_t stream)
{
    const float* meas  = (const float*)d_in[0];
    const float* basis = (const float*)d_in[1];
    const float* rho   = (const float*)d_in[2];
    const float* h0    = (const float*)d_in[3];
    const float* c0    = (const float*)d_in[4];
    const float* cWih  = (const float*)d_in[5];
    const float* cWhh  = (const float*)d_in[6];
    const float* cb    = (const float*)d_in[7];
    const float* pW    = (const float*)d_in[8];
    const float* pb    = (const float*)d_in[9];
    const float* l0Wih = (const float*)d_in[10];
    const float* l0Whh = (const float*)d_in[11];
    const float* l0b   = (const float*)d_in[12];
    const float* l0Whr = (const float*)d_in[13];
    const float* l1Wih = (const float*)d_in[14];
    const float* l1Whh = (const float*)d_in[15];
    const float* l1b   = (const float*)d_in[16];
    const float* l1Whr = (const float*)d_in[17];

    const int B = in_sizes[0];  // 8192

    float* recon = (float*)d_out;                        // B*512 f32
    float* breal = (float*)d_out + (size_t)B * 512;      // B*128 f32 (real parts)

    fused_kernel<<<B / NROW, 256, 0, stream>>>(meas, basis, rho, h0, c0,
                                               cWih, cWhh, cb, pW, pb,
                                               l0Wih, l0Whh, l0b, l0Whr,
                                               l1Wih, l1Whh, l1b, l1Whr,
                                               recon, breal);
}